// Round 12
// baseline (62.377 us; speedup 1.0000x reference)
//
#include <hip/hip_runtime.h>
#include <cstdint>
#include <cstddef>

// NetGrad J = W5 D4 W4 D3 W3 D2 W2 D1 W1, output [B,3,64].
// Fused per-32-sample block (8 phases/CU total, 1 block/CU):
//   8 waves = 2 sample-groups (wgrp=wave>>2: samples wgrp*16..+15)
//           x 4 col-spans   (wn=wave&3: cols wn*64..+63, FN=4).
// Chain rows: wgrp*48 + o*16 + s  (G lane-mapping exact per wave group).
// All-f16 MFMA, permuted column storage (half4 conflict-free LDS writes),
// expand fused into L4 phase. 2 x 96-row arenas ping-pong, 7 barriers.

typedef _Float16 half_t;
typedef __attribute__((ext_vector_type(4))) _Float16 half4;
typedef __attribute__((ext_vector_type(8))) _Float16 half8;
typedef __attribute__((ext_vector_type(4))) float f32x4;

#define MFMA16(a, b, c) __builtin_amdgcn_mfma_f32_16x16x32_f16(a, b, c, 0, 0, 0)

constexpr int Bsz = 8192;
constexpr int LDA = 264;          // LDS row stride in halves (528 B)

// logical k held at storage position p (self-inverse-free bijection on 0..255)
__device__ __forceinline__ int kofp(int p) {
    return (p & 0xC0) | ((p & 3) << 4) | ((p >> 2) & 15);
}

// ---------------- prep: gather-permute all weight tables to f16 ----------------
__global__ __launch_bounds__(256)
void prep(const float* __restrict__ W1, const float* __restrict__ W2,
          const float* __restrict__ W3, const float* __restrict__ W4,
          half_t* W1h, half_t* T1p,
          half_t* W2p, half_t* W3p, half_t* W4p,
          half_t* T2p, half_t* T3p, half_t* T4p)
{
    int idx = blockIdx.x * 256 + threadIdx.x;
    if (idx < 16384) { W1h[idx] = (half_t)W1[idx]; return; }
    idx -= 16384;
    if (idx < 16384) {
        const int j = idx >> 8, p = idx & 255;
        T1p[idx] = (half_t)W1[kofp(p) * 64 + j];
        return;
    }
    idx -= 16384;
    if (idx >= 6 * 65536) return;
    const int t = idx >> 16, i = idx & 65535;
    const int c = i >> 8, p = i & 255, k = kofp(p);
    switch (t) {
        case 0: W2p[i] = (half_t)W2[c * 256 + k]; break;
        case 1: W3p[i] = (half_t)W3[c * 256 + k]; break;
        case 2: W4p[i] = (half_t)W4[c * 256 + k]; break;
        case 3: T2p[i] = (half_t)W2[k * 256 + c]; break;
        case 4: T3p[i] = (half_t)W3[k * 256 + c]; break;
        case 5: T4p[i] = (half_t)W4[k * 256 + c]; break;
    }
}

// ---------------- fwd layer (K=256): pre = A @ Wp^T + b; G->regs; H'->Awr ----------------
template<bool WRITE_H>
__device__ __forceinline__
void fwd_layer_p(const half_t* __restrict__ Ard, half_t* __restrict__ Awr,
                 const half_t* __restrict__ Wp, const float* __restrict__ bias,
                 float gout[4][4], int n0w, int lrow, int kgrp,
                 int hbase, int pbase)
{
    const int arow = (hbase + lrow) * LDA;
    f32x4 acc[4] = {};
    #pragma unroll
    for (int kc = 0; kc < 8; ++kc) {
        const int ko = kc * 32 + kgrp * 8;
        const half8 a = *(const half8*)&Ard[arow + ko];
        #pragma unroll
        for (int fn = 0; fn < 4; ++fn) {
            const half8 b = *(const half8*)(Wp + (size_t)(n0w + fn * 16 + lrow) * 256 + ko);
            acc[fn] = MFMA16(a, b, acc[fn]);
        }
    }
    float hv[4][4];
    #pragma unroll
    for (int fn = 0; fn < 4; ++fn) {
        const float bc = bias[n0w + fn * 16 + lrow];
        #pragma unroll
        for (int r = 0; r < 4; ++r) {
            const float pre = acc[fn][r] + bc;
            float g, h;
            if (pre > 0.f) { g = 1.f; h = pre; }
            else           { g = __expf(pre); h = g - 1.f; }
            gout[fn][r] = g;
            hv[r][fn] = h;
        }
    }
    if constexpr (WRITE_H) {
        #pragma unroll
        for (int r = 0; r < 4; ++r) {
            half4 w = {(half_t)hv[r][0], (half_t)hv[r][1],
                       (half_t)hv[r][2], (half_t)hv[r][3]};
            *(half4*)&Awr[(hbase + kgrp * 4 + r) * LDA + pbase] = w;
        }
        __syncthreads();
    }
}

// ---------------- bwd mid step: Cwr = (Crd @ Tp^T) * G ----------------
__device__ __forceinline__
void bwd_mid(const half_t* __restrict__ Crd, half_t* __restrict__ Cwr,
             const half_t* __restrict__ Tp, const float gpre[4][4],
             int n0w, int lrow, int kgrp, int rbase, int pbase)
{
    const int ar0 = (rbase + lrow) * LDA;
    const int ar1 = (rbase + 16 + lrow) * LDA;
    const int ar2 = (rbase + 32 + lrow) * LDA;
    f32x4 acc[3][4] = {};
    #pragma unroll
    for (int kc = 0; kc < 8; ++kc) {
        const int ko = kc * 32 + kgrp * 8;
        half8 b[4];
        #pragma unroll
        for (int fn = 0; fn < 4; ++fn)
            b[fn] = *(const half8*)(Tp + (size_t)(n0w + fn * 16 + lrow) * 256 + ko);
        const half8 a0 = *(const half8*)&Crd[ar0 + ko];
        const half8 a1 = *(const half8*)&Crd[ar1 + ko];
        const half8 a2 = *(const half8*)&Crd[ar2 + ko];
        __builtin_amdgcn_s_setprio(1);
        #pragma unroll
        for (int fn = 0; fn < 4; ++fn) {
            acc[0][fn] = MFMA16(a0, b[fn], acc[0][fn]);
            acc[1][fn] = MFMA16(a1, b[fn], acc[1][fn]);
            acc[2][fn] = MFMA16(a2, b[fn], acc[2][fn]);
        }
        __builtin_amdgcn_s_setprio(0);
    }
    #pragma unroll
    for (int o = 0; o < 3; ++o)
        #pragma unroll
        for (int r = 0; r < 4; ++r) {
            half4 w = {(half_t)(acc[o][0][r] * gpre[0][r]),
                       (half_t)(acc[o][1][r] * gpre[1][r]),
                       (half_t)(acc[o][2][r] * gpre[2][r]),
                       (half_t)(acc[o][3][r] * gpre[3][r])};
            *(half4*)&Cwr[(rbase + o * 16 + kgrp * 4 + r) * LDA + pbase] = w;
        }
    __syncthreads();
}

// ---------------- fully fused forward+backward, 32 samples/block ----------------
__global__ __launch_bounds__(512, 2)
void netgrad_fused(const float* __restrict__ x,
                   const half_t* __restrict__ W1h, const float* __restrict__ b1,
                   const half_t* __restrict__ W2p, const float* __restrict__ b2,
                   const half_t* __restrict__ W3p, const float* __restrict__ b3,
                   const half_t* __restrict__ W4p, const float* __restrict__ b4,
                   const float* __restrict__ W5,
                   const half_t* __restrict__ T4p, const half_t* __restrict__ T3p,
                   const half_t* __restrict__ T2p, const half_t* __restrict__ T1p,
                   float* __restrict__ out)
{
    __shared__ half_t CA[96 * LDA];
    __shared__ half_t CB[96 * LDA];
    const int tid  = threadIdx.x;
    const int m0s  = blockIdx.x * 32;
    const int lane = tid & 63, lrow = lane & 15, kgrp = lane >> 4;
    const int wave = tid >> 6;
    const int wgrp = wave >> 2;            // sample half: 0 or 1
    const int wn   = wave & 3;             // col span
    const int n0w  = wn * 64;
    const int hbase = wgrp * 16;           // H rows for this group
    const int rbase = wgrp * 48;           // C rows for this group
    const int pbase = (lrow << 2) | (wn << 6);

    float G1r[4][4], G2r[4][4], G3r[4][4], G4r[4][4];

    // ---- L1: A straight from x (K=64 linear; W1h linear) ----
    {
        half8 a[2];
        #pragma unroll
        for (int kc = 0; kc < 2; ++kc) {
            const float* xp = x + (size_t)(m0s + hbase + lrow) * 64 + kc * 32 + kgrp * 8;
            const float4 v0 = *(const float4*)xp;
            const float4 v1 = *(const float4*)(xp + 4);
            a[kc][0] = (half_t)v0.x; a[kc][1] = (half_t)v0.y;
            a[kc][2] = (half_t)v0.z; a[kc][3] = (half_t)v0.w;
            a[kc][4] = (half_t)v1.x; a[kc][5] = (half_t)v1.y;
            a[kc][6] = (half_t)v1.z; a[kc][7] = (half_t)v1.w;
        }
        f32x4 acc[4] = {};
        #pragma unroll
        for (int kc = 0; kc < 2; ++kc)
            #pragma unroll
            for (int fn = 0; fn < 4; ++fn) {
                const half8 b = *(const half8*)(W1h + (size_t)(n0w + fn * 16 + lrow) * 64
                                                + kc * 32 + kgrp * 8);
                acc[fn] = MFMA16(a[kc], b, acc[fn]);
            }
        float hv[4][4];
        #pragma unroll
        for (int fn = 0; fn < 4; ++fn) {
            const float bc = b1[n0w + fn * 16 + lrow];
            #pragma unroll
            for (int r = 0; r < 4; ++r) {
                const float pre = acc[fn][r] + bc;
                float g, h;
                if (pre > 0.f) { g = 1.f; h = pre; }
                else           { g = __expf(pre); h = g - 1.f; }
                G1r[fn][r] = g;
                hv[r][fn] = h;
            }
        }
        #pragma unroll
        for (int r = 0; r < 4; ++r) {
            half4 w = {(half_t)hv[r][0], (half_t)hv[r][1],
                       (half_t)hv[r][2], (half_t)hv[r][3]};
            *(half4*)&CA[(hbase + kgrp * 4 + r) * LDA + pbase] = w;
        }
        __syncthreads();
    }

    // ---- L2..L4: H ping-pong CA->CB->CA, L4 reads CA (no H write) ----
    fwd_layer_p<true >(CA, CB, W2p, b2, G2r, n0w, lrow, kgrp, hbase, pbase);
    fwd_layer_p<true >(CB, CA, W3p, b3, G3r, n0w, lrow, kgrp, hbase, pbase);
    fwd_layer_p<false>(CA, nullptr, W4p, b4, G4r, n0w, lrow, kgrp, hbase, pbase);

    // ---- expand into CB (same phase as L4): CB[rbase+o*16+s][k]=W5[o][k]*G4[s][k] ----
    {
        float w5v[3][4];
        #pragma unroll
        for (int fn = 0; fn < 4; ++fn) {
            const int k = n0w + fn * 16 + lrow;
            #pragma unroll
            for (int o = 0; o < 3; ++o) w5v[o][fn] = W5[o * 256 + k];
        }
        #pragma unroll
        for (int o = 0; o < 3; ++o)
            #pragma unroll
            for (int r = 0; r < 4; ++r) {
                half4 w = {(half_t)(w5v[o][0] * G4r[0][r]),
                           (half_t)(w5v[o][1] * G4r[1][r]),
                           (half_t)(w5v[o][2] * G4r[2][r]),
                           (half_t)(w5v[o][3] * G4r[3][r])};
                *(half4*)&CB[(rbase + o * 16 + kgrp * 4 + r) * LDA + pbase] = w;
            }
        __syncthreads();
    }

    // ---- backward chain: CB -> CA -> CB -> CA ----
    bwd_mid(CB, CA, T4p, G3r, n0w, lrow, kgrp, rbase, pbase);
    bwd_mid(CA, CB, T3p, G2r, n0w, lrow, kgrp, rbase, pbase);
    bwd_mid(CB, CA, T2p, G1r, n0w, lrow, kgrp, rbase, pbase);

    // ---- final: CA group rows @ T1p^T -> out; each wave 16 cols ----
    {
        const int j = wn * 16 + lrow;
        const size_t bcf = (size_t)j * 256;
        f32x4 acc[3] = {};
        #pragma unroll
        for (int kc = 0; kc < 8; ++kc) {
            const int ko = kc * 32 + kgrp * 8;
            const half8 b = *(const half8*)(T1p + bcf + ko);
            acc[0] = MFMA16(*(const half8*)&CA[(rbase + lrow) * LDA + ko],      b, acc[0]);
            acc[1] = MFMA16(*(const half8*)&CA[(rbase + 16 + lrow) * LDA + ko], b, acc[1]);
            acc[2] = MFMA16(*(const half8*)&CA[(rbase + 32 + lrow) * LDA + ko], b, acc[2]);
        }
        #pragma unroll
        for (int o = 0; o < 3; ++o)
            #pragma unroll
            for (int r = 0; r < 4; ++r)
                out[((size_t)(m0s + hbase + kgrp * 4 + r) * 3 + o) * 64 + j] = acc[o][r];
    }
}

extern "C" void kernel_launch(void* const* d_in, const int* in_sizes, int n_in,
                              void* d_out, int out_size, void* d_ws, size_t ws_size,
                              hipStream_t stream)
{
    const float* x  = (const float*)d_in[0];
    const float* W1 = (const float*)d_in[1];
    const float* b1 = (const float*)d_in[2];
    const float* W2 = (const float*)d_in[3];
    const float* b2 = (const float*)d_in[4];
    const float* W3 = (const float*)d_in[5];
    const float* b3 = (const float*)d_in[6];
    const float* W4 = (const float*)d_in[7];
    const float* b4 = (const float*)d_in[8];
    const float* W5 = (const float*)d_in[9];

    // ---- workspace carve (~0.9 MB f16 tables) ----
    char* p = (char*)d_ws;
    half_t* W1h = (half_t*)p; p += 256 * 64 * 2;
    half_t* T1p = (half_t*)p; p += 64 * 256 * 2;
    half_t* W2p = (half_t*)p; p += 256 * 256 * 2;
    half_t* W3p = (half_t*)p; p += 256 * 256 * 2;
    half_t* W4p = (half_t*)p; p += 256 * 256 * 2;
    half_t* T2p = (half_t*)p; p += 256 * 256 * 2;
    half_t* T3p = (half_t*)p; p += 256 * 256 * 2;
    half_t* T4p = (half_t*)p; p += 256 * 256 * 2;

    const int prep_elems = 16384 + 16384 + 6 * 65536;
    prep<<<(prep_elems + 255) / 256, 256, 0, stream>>>(W1, W2, W3, W4,
        W1h, T1p, W2p, W3p, W4p, T2p, T3p, T4p);

    netgrad_fused<<<Bsz / 32, 512, 0, stream>>>(x,
        W1h, b1,  W2p, b2,  W3p, b3,  W4p, b4,
        W5,  T4p, T3p, T2p, T1p,
        (float*)d_out);
}